// Round 2
// baseline (96.408 us; speedup 1.0000x reference)
//
#include <hip/hip_runtime.h>

#define HH 512
#define WW 512
#define CH 3
#define NTX 64          // strips per block row (one wave per y-row)
#define NTY 4           // pixel rows per block
#define PX  4           // pixels per thread (horizontal strip)
#define TILE_W  (NTX * PX + 6)   // 262 used columns
#define TILE_WP 264              // padded stride: multiple of 8 floats -> 16B-aligned rows
#define TILE_H  (NTY + 6)        // 10

// -50/ln2 ... exp(-50*d^2 + lnw) == exp2(K1*d^2 + K2*r2)
#define K1 (-72.13475204444817f)          // -50 * log2(e)
#define K2 (-0.3205988979753252f)         // -(1/4.5) * log2(e)

__device__ __forceinline__ int reflect_idx(int v, int n) {
    v = (v < 0) ? -v : v;
    return (v >= n) ? (2 * (n - 1) - v) : v;
}

__device__ __forceinline__ float fast_exp2(float x) {
#if __has_builtin(__builtin_amdgcn_exp2f)
    return __builtin_amdgcn_exp2f(x);
#else
    return exp2f(x);
#endif
}

__global__ __launch_bounds__(NTX * NTY)
void bilateral_kernel(const float* __restrict__ in, float* __restrict__ out) {
    __shared__ __align__(16) float sm[CH][TILE_H][TILE_WP];

    const int bx0 = blockIdx.x * (NTX * PX);
    const int by0 = blockIdx.y * NTY;
    const int b   = blockIdx.z;
    const float* inb = in + (size_t)b * CH * HH * WW;

    // ---- cooperative halo staging (wave-uniform y-branches, coalesced x) ----
    for (int c = 0; c < CH; ++c) {
        for (int ty = threadIdx.y; ty < TILE_H; ty += NTY) {
            const int gy = reflect_idx(by0 + ty - 3, HH);
            const float* grow = inb + (c * HH + gy) * WW;
            float* srow = &sm[c][ty][0];
            for (int tx = threadIdx.x; tx < TILE_WP; tx += NTX) {
                const int gx = reflect_idx(bx0 + tx - 3, WW);
                srow[tx] = grow[gx];
            }
        }
    }
    __syncthreads();

    const int lx = threadIdx.x;
    const int ly = threadIdx.y;
    const int cb = PX * lx;   // tile column of A[0]; window col for (p,j) = A[p+j]

    float c0[PX], c1[PX], c2[PX];
#pragma unroll
    for (int p = 0; p < PX; ++p) {
        c0[p] = sm[0][ly + 3][cb + 3 + p];
        c1[p] = sm[1][ly + 3][cb + 3 + p];
        c2[p] = sm[2][ly + 3][cb + 3 + p];
    }

    float n0[PX] = {0,0,0,0}, n1[PX] = {0,0,0,0}, n2[PX] = {0,0,0,0}, den[PX] = {0,0,0,0};

#pragma unroll
    for (int i = 0; i < 7; ++i) {
        // 12 columns per channel via 3 aligned ds_read_b128 each
        float A0[12], A1[12], A2[12];
#define LOADROW(DST, CHI)                                                        \
        {                                                                        \
            const float4 q0 = *reinterpret_cast<const float4*>(&sm[CHI][ly + i][cb]);      \
            const float4 q1 = *reinterpret_cast<const float4*>(&sm[CHI][ly + i][cb + 4]);  \
            const float4 q2 = *reinterpret_cast<const float4*>(&sm[CHI][ly + i][cb + 8]);  \
            DST[0] = q0.x; DST[1] = q0.y; DST[2]  = q0.z; DST[3]  = q0.w;        \
            DST[4] = q1.x; DST[5] = q1.y; DST[6]  = q1.z; DST[7]  = q1.w;        \
            DST[8] = q2.x; DST[9] = q2.y; DST[10] = q2.z; DST[11] = q2.w;        \
        }
        LOADROW(A0, 0)
        LOADROW(A1, 1)
        LOADROW(A2, 2)
#undef LOADROW

#pragma unroll
        for (int p = 0; p < PX; ++p) {
#pragma unroll
            for (int j = 0; j < 7; ++j) {
                const float v0 = A0[p + j];
                const float v1 = A1[p + j];
                const float v2 = A2[p + j];
                const float d  = fabsf(v0 - c0[p]) + fabsf(v1 - c1[p]) + fabsf(v2 - c2[p]);
                // spatial log2-weight folded at compile time
                const float r2 = (float)((i - 3) * (i - 3) + (j - 3) * (j - 3));
                const float w  = fast_exp2(fmaf(d * d, K1, r2 * K2));
                n0[p]  = fmaf(w, v0, n0[p]);
                n1[p]  = fmaf(w, v1, n1[p]);
                n2[p]  = fmaf(w, v2, n2[p]);
                den[p] += w;
            }
        }
    }

    const int y  = by0 + ly;
    const int x0 = bx0 + PX * lx;
    float* outb = out + (size_t)b * CH * HH * WW;

    float inv[PX];
#pragma unroll
    for (int p = 0; p < PX; ++p) inv[p] = 1.0f / den[p];   // den >= 1 (center tap w == 1)

    float4 o;
    o.x = n0[0] * inv[0]; o.y = n0[1] * inv[1]; o.z = n0[2] * inv[2]; o.w = n0[3] * inv[3];
    *reinterpret_cast<float4*>(&outb[(0 * HH + y) * WW + x0]) = o;
    o.x = n1[0] * inv[0]; o.y = n1[1] * inv[1]; o.z = n1[2] * inv[2]; o.w = n1[3] * inv[3];
    *reinterpret_cast<float4*>(&outb[(1 * HH + y) * WW + x0]) = o;
    o.x = n2[0] * inv[0]; o.y = n2[1] * inv[1]; o.z = n2[2] * inv[2]; o.w = n2[3] * inv[3];
    *reinterpret_cast<float4*>(&outb[(2 * HH + y) * WW + x0]) = o;
}

extern "C" void kernel_launch(void* const* d_in, const int* in_sizes, int n_in,
                              void* d_out, int out_size, void* d_ws, size_t ws_size,
                              hipStream_t stream) {
    const float* in = (const float*)d_in[0];
    float* out = (float*)d_out;
    const int B = in_sizes[0] / (CH * HH * WW);
    dim3 grid(WW / (NTX * PX), HH / NTY, B);
    dim3 block(NTX, NTY, 1);
    bilateral_kernel<<<grid, block, 0, stream>>>(in, out);
}

// Round 3
// 88.720 us; speedup vs baseline: 1.0866x; 1.0866x over previous
//
#include <hip/hip_runtime.h>

#define HH 512
#define WW 512
#define CH 3
#define NTX 64          // lanes per row (one wave per y-row)
#define NTY 8           // pixel rows per block
#define PX  2           // pixels per thread
#define SPAN (NTX * PX)          // 128 pixels per block row
#define TILE_W  (SPAN + 6)       // 134 used columns
#define TILE_WP 136              // padded stride (16B-aligned rows: 544 B)
#define TILE_H  (NTY + 6)        // 14

// exp(-50*d^2) * exp(-r2/4.5)  ==  exp2(K1*d^2 + K2*r2)
#define K1 (-72.13475204444817f)   // -50 * log2(e)
#define K2 (-0.3205988979753252f)  // -(1/4.5) * log2(e)

__device__ __forceinline__ int reflect_idx(int v, int n) {
    v = (v < 0) ? -v : v;
    return (v >= n) ? (2 * (n - 1) - v) : v;
}

__device__ __forceinline__ float fast_exp2(float x) {
#if __has_builtin(__builtin_amdgcn_exp2f)
    return __builtin_amdgcn_exp2f(x);
#else
    return exp2f(x);
#endif
}

__global__ __launch_bounds__(NTX * NTY)
void bilateral_kernel(const float* __restrict__ in, float* __restrict__ out) {
    __shared__ __align__(16) float sm[CH][TILE_H][TILE_WP];

    const int bx0 = blockIdx.x * SPAN;
    const int by0 = blockIdx.y * NTY;
    const int b   = blockIdx.z;
    const float* inb = in + (size_t)b * CH * HH * WW;

    // ---- cooperative halo staging (stride-1 b32 across lanes: conflict-free) ----
    for (int c = 0; c < CH; ++c) {
        for (int ty = threadIdx.y; ty < TILE_H; ty += NTY) {
            const int gy = reflect_idx(by0 + ty - 3, HH);
            const float* grow = inb + (c * HH + gy) * WW;
            float* srow = &sm[c][ty][0];
            for (int tx = threadIdx.x; tx < TILE_WP; tx += NTX) {
                const int gx = reflect_idx(bx0 + tx - 3, WW);
                srow[tx] = grow[gx];
            }
        }
    }
    __syncthreads();

    const int lx = threadIdx.x;
    const int ly = threadIdx.y;
    const int cb = PX * lx;   // A[k] = sm[c][ly+i][cb+k], k = 0..7; tap (p,j) uses A[p+j]

    float c0[PX], c1[PX], c2[PX];
#pragma unroll
    for (int p = 0; p < PX; ++p) {
        c0[p] = sm[0][ly + 3][cb + 3 + p];
        c1[p] = sm[1][ly + 3][cb + 3 + p];
        c2[p] = sm[2][ly + 3][cb + 3 + p];
    }

    float n0[PX] = {0, 0}, n1[PX] = {0, 0}, n2[PX] = {0, 0}, den[PX] = {0, 0};

#pragma unroll
    for (int i = 0; i < 7; ++i) {
        // hoist this row's 8 floats per channel into registers (4x ds_read_b64 each,
        // lane stride 8B -> contiguous dwords across the wave, no conflicts)
        float A0[8], A1[8], A2[8];
#pragma unroll
        for (int k = 0; k < 4; ++k) {
            const float2 q0 = *reinterpret_cast<const float2*>(&sm[0][ly + i][cb + 2 * k]);
            const float2 q1 = *reinterpret_cast<const float2*>(&sm[1][ly + i][cb + 2 * k]);
            const float2 q2 = *reinterpret_cast<const float2*>(&sm[2][ly + i][cb + 2 * k]);
            A0[2 * k] = q0.x; A0[2 * k + 1] = q0.y;
            A1[2 * k] = q1.x; A1[2 * k + 1] = q1.y;
            A2[2 * k] = q2.x; A2[2 * k + 1] = q2.y;
        }

#pragma unroll
        for (int j = 0; j < 7; ++j) {
#pragma unroll
            for (int p = 0; p < PX; ++p) {
                const float v0 = A0[j + p];
                const float v1 = A1[j + p];
                const float v2 = A2[j + p];
                const float d  = fabsf(v0 - c0[p]) + fabsf(v1 - c1[p]) + fabsf(v2 - c2[p]);
                const float r2 = (float)((i - 3) * (i - 3) + (j - 3) * (j - 3));
                const float w  = fast_exp2(fmaf(d * d, K1, r2 * K2));
                n0[p]  = fmaf(w, v0, n0[p]);
                n1[p]  = fmaf(w, v1, n1[p]);
                n2[p]  = fmaf(w, v2, n2[p]);
                den[p] += w;
            }
        }
    }

    const int y  = by0 + ly;
    const int x0 = bx0 + cb;
    float* outb = out + (size_t)b * CH * HH * WW;

    float inv[PX];
#pragma unroll
    for (int p = 0; p < PX; ++p) inv[p] = 1.0f / den[p];   // den >= 1 (center tap w == 1)

    float2 o;
    o.x = n0[0] * inv[0]; o.y = n0[1] * inv[1];
    *reinterpret_cast<float2*>(&outb[(0 * HH + y) * WW + x0]) = o;
    o.x = n1[0] * inv[0]; o.y = n1[1] * inv[1];
    *reinterpret_cast<float2*>(&outb[(1 * HH + y) * WW + x0]) = o;
    o.x = n2[0] * inv[0]; o.y = n2[1] * inv[1];
    *reinterpret_cast<float2*>(&outb[(2 * HH + y) * WW + x0]) = o;
}

extern "C" void kernel_launch(void* const* d_in, const int* in_sizes, int n_in,
                              void* d_out, int out_size, void* d_ws, size_t ws_size,
                              hipStream_t stream) {
    const float* in = (const float*)d_in[0];
    float* out = (float*)d_out;
    const int B = in_sizes[0] / (CH * HH * WW);
    dim3 grid(WW / SPAN, HH / NTY, B);
    dim3 block(NTX, NTY, 1);
    bilateral_kernel<<<grid, block, 0, stream>>>(in, out);
}

// Round 4
// 62.006 us; speedup vs baseline: 1.5548x; 1.4308x over previous
//
#include <hip/hip_runtime.h>

#define HH 512
#define WW 512
#define CH 3
#define NTX 64          // lanes per row (one wave per y-row)
#define NTY 4           // pixel rows per block
#define PX  2           // pixels per thread
#define SPAN (NTX * PX)          // 128 pixels per block row
#define TILE_W  (SPAN + 6)       // 134 logical columns
#define TILE_H  (NTY + 6)        // 10
#define PHYS_W  138              // 133 + (133>>5) = 137 max phys index -> 138 slots

// exp(-50*d^2) * exp(-r2/4.5)  ==  exp2(K1*d^2 + K2*r2)
#define K1f (-72.13475204444817f)   // -50 * log2(e)
#define K2f (-0.3205988979753252f)  // -(1/4.5) * log2(e)

__device__ __forceinline__ int reflect_idx(int v, int n) {
    v = (v < 0) ? -v : v;
    return (v >= n) ? (2 * (n - 1) - v) : v;
}

__device__ __forceinline__ float fast_exp2(float x) {
#if __has_builtin(__builtin_amdgcn_exp2f)
    return __builtin_amdgcn_exp2f(x);
#else
    return exp2f(x);
#endif
}

// skewed physical column: +1 slot every 32 -> stride-2 lane reads become 2-way (free)
__device__ __forceinline__ int phys(int c) { return c + (c >> 5); }

__global__ __launch_bounds__(NTX * NTY)
void bilateral_kernel(const float* __restrict__ in, float* __restrict__ out) {
    __shared__ float sm[CH * TILE_H * PHYS_W];   // 16560 B

    const int bx0 = blockIdx.x * SPAN;
    const int by0 = blockIdx.y * NTY;
    const int b   = blockIdx.z;
    const float* inb = in + (size_t)b * CH * HH * WW;

    // ---- cooperative halo staging (lane-stride-1 writes, skewed slot: conflict-free) ----
    for (int c = 0; c < CH; ++c) {
        for (int ty = threadIdx.y; ty < TILE_H; ty += NTY) {
            const int gy = reflect_idx(by0 + ty - 3, HH);
            const float* grow = inb + (c * HH + gy) * WW;
            float* srow = &sm[(c * TILE_H + ty) * PHYS_W];
            for (int tx = threadIdx.x; tx < TILE_W; tx += NTX) {
                const int gx = reflect_idx(bx0 + tx - 3, WW);
                srow[phys(tx)] = grow[gx];
            }
        }
    }
    __syncthreads();

    const int lx = threadIdx.x;
    const int ty = threadIdx.y;
    const int cb = PX * lx;   // window cols for (p,j) = cb + j + p, j=0..6, p=0..1 -> cb+0..cb+7

    // per-lane skewed column offsets, computed ONCE; all reads below use imm offsets
    int pcol[8];
#pragma unroll
    for (int k = 0; k < 8; ++k) pcol[k] = phys(cb + k);

    const float* smb = sm + ty * PHYS_W;  // row base for this thread's y

    float c0[PX], c1[PX], c2[PX];
#pragma unroll
    for (int p = 0; p < PX; ++p) {
        c0[p] = smb[(0 * TILE_H + 3) * PHYS_W + pcol[3 + p]];
        c1[p] = smb[(1 * TILE_H + 3) * PHYS_W + pcol[3 + p]];
        c2[p] = smb[(2 * TILE_H + 3) * PHYS_W + pcol[3 + p]];
    }

    float n0[PX] = {0, 0}, n1[PX] = {0, 0}, n2[PX] = {0, 0}, den[PX] = {0, 0};

#pragma unroll
    for (int i = 0; i < 7; ++i) {
        float A0[8], A1[8], A2[8];
#pragma unroll
        for (int k = 0; k < 8; ++k) {
            A0[k] = smb[(0 * TILE_H + i) * PHYS_W + pcol[k]];
            A1[k] = smb[(1 * TILE_H + i) * PHYS_W + pcol[k]];
            A2[k] = smb[(2 * TILE_H + i) * PHYS_W + pcol[k]];
        }

#pragma unroll
        for (int j = 0; j < 7; ++j) {
#pragma unroll
            for (int p = 0; p < PX; ++p) {
                const float v0 = A0[j + p];
                const float v1 = A1[j + p];
                const float v2 = A2[j + p];
                const float d  = fabsf(v0 - c0[p]) + fabsf(v1 - c1[p]) + fabsf(v2 - c2[p]);
                const float lnw = (float)((i - 3) * (i - 3) + (j - 3) * (j - 3)) * K2f;
                const float w  = fast_exp2(fmaf(d * K1f, d, lnw));
                n0[p]  = fmaf(w, v0, n0[p]);
                n1[p]  = fmaf(w, v1, n1[p]);
                n2[p]  = fmaf(w, v2, n2[p]);
                den[p] += w;
            }
        }
    }

    const int y  = by0 + ty;
    const int x0 = bx0 + cb;
    float* outb = out + (size_t)b * CH * HH * WW;

    float inv[PX];
#pragma unroll
    for (int p = 0; p < PX; ++p) inv[p] = 1.0f / den[p];   // den >= 1 (center tap w == 1)

    float2 o;
    o.x = n0[0] * inv[0]; o.y = n0[1] * inv[1];
    *reinterpret_cast<float2*>(&outb[(0 * HH + y) * WW + x0]) = o;
    o.x = n1[0] * inv[0]; o.y = n1[1] * inv[1];
    *reinterpret_cast<float2*>(&outb[(1 * HH + y) * WW + x0]) = o;
    o.x = n2[0] * inv[0]; o.y = n2[1] * inv[1];
    *reinterpret_cast<float2*>(&outb[(2 * HH + y) * WW + x0]) = o;
}

extern "C" void kernel_launch(void* const* d_in, const int* in_sizes, int n_in,
                              void* d_out, int out_size, void* d_ws, size_t ws_size,
                              hipStream_t stream) {
    const float* in = (const float*)d_in[0];
    float* out = (float*)d_out;
    const int B = in_sizes[0] / (CH * HH * WW);
    dim3 grid(WW / SPAN, HH / NTY, B);
    dim3 block(NTX, NTY, 1);
    bilateral_kernel<<<grid, block, 0, stream>>>(in, out);
}